// Round 1
// baseline (177.965 us; speedup 1.0000x reference)
//
#include <hip/hip_runtime.h>
#include <math.h>

// Item_Graph: 2-layer fixed-degree GCN over KNN graph.
// N=100000, D=128, K=5. Edge weight is the CONSTANT w = 1/(5+1e-7)
// (row_sum is exactly K for every row). So:
//   x1 = w * gather-sum(x0);  out = x0 + x1 + w * gather-sum(x1)
// Layer layout: one 32-lane group per row, float4 per lane (32*16B = 512B row).

#define GCN_K 5
#define D4 32  // 128 floats = 32 float4

__global__ __launch_bounds__(256) void gcn_layer1(
    const float4* __restrict__ x0, const int* __restrict__ knn,
    float4* __restrict__ x1, float w, int n) {
  int t = blockIdx.x * 256 + threadIdx.x;
  int row = t >> 5;
  if (row >= n) return;
  int c = t & 31;
  const int* kp = knn + row * GCN_K;
  float4 s = make_float4(0.f, 0.f, 0.f, 0.f);
#pragma unroll
  for (int k = 0; k < GCN_K; ++k) {
    int j = kp[k];
    float4 v = x0[(size_t)j * D4 + c];
    s.x += v.x; s.y += v.y; s.z += v.z; s.w += v.w;
  }
  s.x *= w; s.y *= w; s.z *= w; s.w *= w;
  x1[(size_t)row * D4 + c] = s;
}

__global__ __launch_bounds__(256) void gcn_layer2(
    const float4* __restrict__ x0, const float4* __restrict__ x1,
    const int* __restrict__ knn, float4* __restrict__ out, float w, int n) {
  int t = blockIdx.x * 256 + threadIdx.x;
  int row = t >> 5;
  if (row >= n) return;
  int c = t & 31;
  const int* kp = knn + row * GCN_K;
  float4 s = make_float4(0.f, 0.f, 0.f, 0.f);
#pragma unroll
  for (int k = 0; k < GCN_K; ++k) {
    int j = kp[k];
    float4 v = x1[(size_t)j * D4 + c];
    s.x += v.x; s.y += v.y; s.z += v.z; s.w += v.w;
  }
  float4 a = x0[(size_t)row * D4 + c];
  float4 b = x1[(size_t)row * D4 + c];
  float4 o;
  o.x = a.x + b.x + w * s.x;
  o.y = a.y + b.y + w * s.y;
  o.z = a.z + b.z + w * s.z;
  o.w = a.w + b.w + w * s.w;
  out[(size_t)row * D4 + c] = o;
}

extern "C" void kernel_launch(void* const* d_in, const int* in_sizes, int n_in,
                              void* d_out, int out_size, void* d_ws, size_t ws_size,
                              hipStream_t stream) {
  const float* x0 = (const float*)d_in[0];
  const int* knn = (const int*)d_in[1];
  float* out = (float*)d_out;
  float* x1 = (float*)d_ws;  // N*128 floats = 51.2 MB staging for layer-1 output

  int n = in_sizes[0] / 128;  // N items

  // Match reference numerics: r = (K + 1e-7)^-0.5 in fp32; w = r*r.
  float r = powf(5.0f + 1e-7f, -0.5f);
  float w = r * r;

  int total = n * 32;  // 32 lanes per row
  int blocks = (total + 255) / 256;
  gcn_layer1<<<blocks, 256, 0, stream>>>((const float4*)x0, knn, (float4*)x1, w, n);
  gcn_layer2<<<blocks, 256, 0, stream>>>((const float4*)x0, (const float4*)x1, knn,
                                         (float4*)out, w, n);
}

// Round 3
// 151.977 us; speedup vs baseline: 1.1710x; 1.1710x over previous
//
#include <hip/hip_runtime.h>
#include <math.h>

// Item_Graph: 2-layer fixed-degree GCN over KNN graph.
// N=100000, D=128, K=5. Edge weight is the CONSTANT w = 1/(5+1e-7).
//   x1 = w * gather-sum(x0);  out = x0 + x1 + w * gather-sum(x1)
// R3: = R2 (bf16 x1 staging, nontemporal out store) with the nontemporal
// store going through a clang native vector type (HIP float4 class is
// rejected by __builtin_nontemporal_store).

#define GCN_K 5
#define D4 32  // 128 floats = 32 float4 lanes per row

typedef float f32x4 __attribute__((ext_vector_type(4)));

static __device__ __forceinline__ ushort f2bf(float f) {
  unsigned u = __float_as_uint(f);
  u = (u + 0x7fffu + ((u >> 16) & 1u)) >> 16;  // RTNE (no NaN inputs here)
  return (ushort)u;
}
static __device__ __forceinline__ float bf2f(ushort u) {
  return __uint_as_float(((unsigned)u) << 16);
}

__global__ __launch_bounds__(256) void gcn_layer1(
    const float4* __restrict__ x0, const int* __restrict__ knn,
    ushort4* __restrict__ x1, float w, int n) {
  int t = blockIdx.x * 256 + threadIdx.x;
  int row = t >> 5;
  if (row >= n) return;
  int c = t & 31;
  const int* kp = knn + row * GCN_K;
  float4 s = make_float4(0.f, 0.f, 0.f, 0.f);
#pragma unroll
  for (int k = 0; k < GCN_K; ++k) {
    int j = kp[k];
    float4 v = x0[(size_t)j * D4 + c];
    s.x += v.x; s.y += v.y; s.z += v.z; s.w += v.w;
  }
  ushort4 p;
  p.x = f2bf(w * s.x); p.y = f2bf(w * s.y);
  p.z = f2bf(w * s.z); p.w = f2bf(w * s.w);
  x1[(size_t)row * D4 + c] = p;  // row = 32 lanes x 8B = 256B, coalesced
}

__global__ __launch_bounds__(256) void gcn_layer2(
    const float4* __restrict__ x0, const ushort4* __restrict__ x1,
    const int* __restrict__ knn, float* __restrict__ out, float w, int n) {
  int t = blockIdx.x * 256 + threadIdx.x;
  int row = t >> 5;
  if (row >= n) return;
  int c = t & 31;
  const int* kp = knn + row * GCN_K;
  float4 s = make_float4(0.f, 0.f, 0.f, 0.f);
#pragma unroll
  for (int k = 0; k < GCN_K; ++k) {
    int j = kp[k];
    ushort4 v = x1[(size_t)j * D4 + c];
    s.x += bf2f(v.x); s.y += bf2f(v.y); s.z += bf2f(v.z); s.w += bf2f(v.w);
  }
  float4 a = x0[(size_t)row * D4 + c];
  ushort4 bq = x1[(size_t)row * D4 + c];
  f32x4 o;
  o.x = a.x + bf2f(bq.x) + w * s.x;
  o.y = a.y + bf2f(bq.y) + w * s.y;
  o.z = a.z + bf2f(bq.z) + w * s.z;
  o.w = a.w + bf2f(bq.w) + w * s.w;
  f32x4* op = (f32x4*)(out + ((size_t)row * D4 + c) * 4);
  __builtin_nontemporal_store(o, op);
}

extern "C" void kernel_launch(void* const* d_in, const int* in_sizes, int n_in,
                              void* d_out, int out_size, void* d_ws, size_t ws_size,
                              hipStream_t stream) {
  const float* x0 = (const float*)d_in[0];
  const int* knn = (const int*)d_in[1];
  float* out = (float*)d_out;
  ushort4* x1 = (ushort4*)d_ws;  // N*128 bf16 = 25.6 MB staging

  int n = in_sizes[0] / 128;  // N items

  float r = powf(5.0f + 1e-7f, -0.5f);
  float w = r * r;

  int total = n * 32;
  int blocks = (total + 255) / 256;
  gcn_layer1<<<blocks, 256, 0, stream>>>((const float4*)x0, knn, x1, w, n);
  gcn_layer2<<<blocks, 256, 0, stream>>>((const float4*)x0, x1, knn,
                                         out, w, n);
}

// Round 4
// 150.347 us; speedup vs baseline: 1.1837x; 1.0108x over previous
//
#include <hip/hip_runtime.h>
#include <math.h>

// Item_Graph: 2-layer fixed-degree GCN over KNN graph.
// N=100000, D=128, K=5. Edge weight is the CONSTANT w = 1/(5+1e-7).
//   x1 = w * gather-sum(x0);  out = x0 + x1 + w * gather-sum(x1)
// R4: (a) pre-convert x0 -> y0 bf16 so layer1's gather is bf16 too
//     (halves layer1 gather bytes; footprint 25.6MB improves cache hit);
//     (b) 16 lanes/row x 16B/lane layout -> 4 rows/wave = 2x gather MLP.
// Error budget: bf16 on x0-gather adds ~0.02; predicted absmax ~0.05 vs
// threshold 0.116.

#define GCN_K 5

typedef float f32x4 __attribute__((ext_vector_type(4)));
typedef ushort u16x8 __attribute__((ext_vector_type(8)));  // 16B = 8 bf16

static __device__ __forceinline__ ushort f2bf(float f) {
  unsigned u = __float_as_uint(f);
  u = (u + 0x7fffu + ((u >> 16) & 1u)) >> 16;  // RTNE (no NaN inputs here)
  return (ushort)u;
}
static __device__ __forceinline__ float bf2f(ushort u) {
  return __uint_as_float(((unsigned)u) << 16);
}

// Streaming convert: y0 = bf16(x0). 8 floats per thread.
__global__ __launch_bounds__(256) void cvt_bf16(
    const f32x4* __restrict__ x0, u16x8* __restrict__ y0, int n8) {
  int t = blockIdx.x * 256 + threadIdx.x;
  if (t >= n8) return;
  f32x4 a = x0[2 * t];
  f32x4 b = x0[2 * t + 1];
  u16x8 p;
  p[0] = f2bf(a.x); p[1] = f2bf(a.y); p[2] = f2bf(a.z); p[3] = f2bf(a.w);
  p[4] = f2bf(b.x); p[5] = f2bf(b.y); p[6] = f2bf(b.z); p[7] = f2bf(b.w);
  y0[t] = p;
}

// x1 = bf16(w * gather-sum(y0)). 16 lanes/row, 16B/lane.
__global__ __launch_bounds__(256) void gcn_layer1(
    const u16x8* __restrict__ y0, const int* __restrict__ knn,
    u16x8* __restrict__ x1, float w, int n) {
  int t = blockIdx.x * 256 + threadIdx.x;
  int row = t >> 4;
  if (row >= n) return;
  int c = t & 15;
  const int* kp = knn + row * GCN_K;
  float s[8] = {0.f, 0.f, 0.f, 0.f, 0.f, 0.f, 0.f, 0.f};
#pragma unroll
  for (int k = 0; k < GCN_K; ++k) {
    int j = kp[k];
    u16x8 v = y0[(size_t)j * 16 + c];
#pragma unroll
    for (int e = 0; e < 8; ++e) s[e] += bf2f(v[e]);
  }
  u16x8 p;
#pragma unroll
  for (int e = 0; e < 8; ++e) p[e] = f2bf(w * s[e]);
  x1[(size_t)row * 16 + c] = p;  // 16 lanes x 16B = 256B/row, coalesced
}

// out = x0 + x1 + w * gather-sum(x1). 16 lanes/row, 8 floats/lane.
__global__ __launch_bounds__(256) void gcn_layer2(
    const f32x4* __restrict__ x0, const u16x8* __restrict__ x1,
    const int* __restrict__ knn, float* __restrict__ out, float w, int n) {
  int t = blockIdx.x * 256 + threadIdx.x;
  int row = t >> 4;
  if (row >= n) return;
  int c = t & 15;
  const int* kp = knn + row * GCN_K;
  float s[8] = {0.f, 0.f, 0.f, 0.f, 0.f, 0.f, 0.f, 0.f};
#pragma unroll
  for (int k = 0; k < GCN_K; ++k) {
    int j = kp[k];
    u16x8 v = x1[(size_t)j * 16 + c];
#pragma unroll
    for (int e = 0; e < 8; ++e) s[e] += bf2f(v[e]);
  }
  f32x4 a0 = x0[(size_t)row * 32 + 2 * c];
  f32x4 a1 = x0[(size_t)row * 32 + 2 * c + 1];
  u16x8 b = x1[(size_t)row * 16 + c];
  f32x4 o0, o1;
  o0.x = a0.x + bf2f(b[0]) + w * s[0];
  o0.y = a0.y + bf2f(b[1]) + w * s[1];
  o0.z = a0.z + bf2f(b[2]) + w * s[2];
  o0.w = a0.w + bf2f(b[3]) + w * s[3];
  o1.x = a1.x + bf2f(b[4]) + w * s[4];
  o1.y = a1.y + bf2f(b[5]) + w * s[5];
  o1.z = a1.z + bf2f(b[6]) + w * s[6];
  o1.w = a1.w + bf2f(b[7]) + w * s[7];
  f32x4* op = (f32x4*)(out + (size_t)row * 128 + c * 8);
  __builtin_nontemporal_store(o0, op);      // out is write-once stream:
  __builtin_nontemporal_store(o1, op + 1);  // keep L2/L3 for the gathers
}

extern "C" void kernel_launch(void* const* d_in, const int* in_sizes, int n_in,
                              void* d_out, int out_size, void* d_ws, size_t ws_size,
                              hipStream_t stream) {
  const float* x0 = (const float*)d_in[0];
  const int* knn = (const int*)d_in[1];
  float* out = (float*)d_out;

  int n = in_sizes[0] / 128;  // N items
  // ws layout: y0 (bf16 copy of x0, 25.6MB) | x1 (bf16 layer-1 out, 25.6MB)
  u16x8* y0 = (u16x8*)d_ws;
  u16x8* x1 = (u16x8*)((char*)d_ws + (size_t)n * 128 * 2);

  float r = powf(5.0f + 1e-7f, -0.5f);
  float w = r * r;

  int n8 = n * 16;  // n*128/8 vector-of-8 chunks == n*16 threads
  int blocks = (n8 + 255) / 256;
  cvt_bf16<<<blocks, 256, 0, stream>>>((const f32x4*)x0, y0, n8);
  gcn_layer1<<<blocks, 256, 0, stream>>>(y0, knn, x1, w, n);
  gcn_layer2<<<blocks, 256, 0, stream>>>((const f32x4*)x0, x1, knn, out, w, n);
}

// Round 5
// 149.979 us; speedup vs baseline: 1.1866x; 1.0025x over previous
//
#include <hip/hip_runtime.h>
#include <math.h>

// Item_Graph: 2-layer fixed-degree GCN over KNN graph.
// N=100000, D=128, K=5. Edge weight is the CONSTANT w = 1/(5+1e-7).
//   x1 = w * gather-sum(x0);  out = x0 + x1 + w * gather-sum(x1)
// R5: knn indices via shuffle-broadcast (lane c<5 loads one index, 5x
// __shfl width-16) instead of 5 redundant dword loads per lane. Cuts
// per-layer VMEM ops ~45% (was ~16M: 8M gathers + 8M knn loads).
// Layout: 16 lanes/row x 16B/lane; x0/x1 staged bf16 (R4).

#define GCN_K 5

typedef float f32x4 __attribute__((ext_vector_type(4)));
typedef ushort u16x8 __attribute__((ext_vector_type(8)));  // 16B = 8 bf16

static __device__ __forceinline__ ushort f2bf(float f) {
  unsigned u = __float_as_uint(f);
  u = (u + 0x7fffu + ((u >> 16) & 1u)) >> 16;  // RTNE (no NaN inputs here)
  return (ushort)u;
}
static __device__ __forceinline__ float bf2f(ushort u) {
  return __uint_as_float(((unsigned)u) << 16);
}

// Streaming convert: y0 = bf16(x0). 8 floats per thread.
__global__ __launch_bounds__(256) void cvt_bf16(
    const f32x4* __restrict__ x0, u16x8* __restrict__ y0, int n8) {
  int t = blockIdx.x * 256 + threadIdx.x;
  if (t >= n8) return;
  f32x4 a = x0[2 * t];
  f32x4 b = x0[2 * t + 1];
  u16x8 p;
  p[0] = f2bf(a.x); p[1] = f2bf(a.y); p[2] = f2bf(a.z); p[3] = f2bf(a.w);
  p[4] = f2bf(b.x); p[5] = f2bf(b.y); p[6] = f2bf(b.z); p[7] = f2bf(b.w);
  y0[t] = p;
}

// x1 = bf16(w * gather-sum(y0)). 16 lanes/row, 16B/lane.
__global__ __launch_bounds__(256) void gcn_layer1(
    const u16x8* __restrict__ y0, const int* __restrict__ knn,
    u16x8* __restrict__ x1, float w, int n) {
  int t = blockIdx.x * 256 + threadIdx.x;
  int row = t >> 4;
  if (row >= n) return;  // whole 16-lane group exits together (same row)
  int c = t & 15;
  int jv = 0;
  if (c < GCN_K) jv = knn[row * GCN_K + c];  // 5 loads per 16 lanes
  int j0 = __shfl(jv, 0, 16);
  int j1 = __shfl(jv, 1, 16);
  int j2 = __shfl(jv, 2, 16);
  int j3 = __shfl(jv, 3, 16);
  int j4 = __shfl(jv, 4, 16);
  u16x8 v0 = y0[(size_t)j0 * 16 + c];
  u16x8 v1 = y0[(size_t)j1 * 16 + c];
  u16x8 v2 = y0[(size_t)j2 * 16 + c];
  u16x8 v3 = y0[(size_t)j3 * 16 + c];
  u16x8 v4 = y0[(size_t)j4 * 16 + c];
  u16x8 p;
#pragma unroll
  for (int e = 0; e < 8; ++e) {
    float s = bf2f(v0[e]) + bf2f(v1[e]) + bf2f(v2[e]) + bf2f(v3[e]) +
              bf2f(v4[e]);
    p[e] = f2bf(w * s);
  }
  x1[(size_t)row * 16 + c] = p;  // 16 lanes x 16B = 256B/row, coalesced
}

// out = x0 + x1 + w * gather-sum(x1). 16 lanes/row, 8 floats/lane.
__global__ __launch_bounds__(256) void gcn_layer2(
    const f32x4* __restrict__ x0, const u16x8* __restrict__ x1,
    const int* __restrict__ knn, float* __restrict__ out, float w, int n) {
  int t = blockIdx.x * 256 + threadIdx.x;
  int row = t >> 4;
  if (row >= n) return;
  int c = t & 15;
  int jv = 0;
  if (c < GCN_K) jv = knn[row * GCN_K + c];
  int j0 = __shfl(jv, 0, 16);
  int j1 = __shfl(jv, 1, 16);
  int j2 = __shfl(jv, 2, 16);
  int j3 = __shfl(jv, 3, 16);
  int j4 = __shfl(jv, 4, 16);
  u16x8 v0 = x1[(size_t)j0 * 16 + c];
  u16x8 v1 = x1[(size_t)j1 * 16 + c];
  u16x8 v2 = x1[(size_t)j2 * 16 + c];
  u16x8 v3 = x1[(size_t)j3 * 16 + c];
  u16x8 v4 = x1[(size_t)j4 * 16 + c];
  f32x4 a0 = x0[(size_t)row * 32 + 2 * c];
  f32x4 a1 = x0[(size_t)row * 32 + 2 * c + 1];
  u16x8 b = x1[(size_t)row * 16 + c];
  float o[8];
#pragma unroll
  for (int e = 0; e < 8; ++e) {
    float s = bf2f(v0[e]) + bf2f(v1[e]) + bf2f(v2[e]) + bf2f(v3[e]) +
              bf2f(v4[e]);
    o[e] = bf2f(b[e]) + w * s;
  }
  f32x4 q0, q1;
  q0.x = a0.x + o[0]; q0.y = a0.y + o[1];
  q0.z = a0.z + o[2]; q0.w = a0.w + o[3];
  q1.x = a1.x + o[4]; q1.y = a1.y + o[5];
  q1.z = a1.z + o[6]; q1.w = a1.w + o[7];
  f32x4* op = (f32x4*)(out + (size_t)row * 128 + c * 8);
  __builtin_nontemporal_store(q0, op);      // out is write-once stream:
  __builtin_nontemporal_store(q1, op + 1);  // keep L2/L3 for the gathers
}

extern "C" void kernel_launch(void* const* d_in, const int* in_sizes, int n_in,
                              void* d_out, int out_size, void* d_ws, size_t ws_size,
                              hipStream_t stream) {
  const float* x0 = (const float*)d_in[0];
  const int* knn = (const int*)d_in[1];
  float* out = (float*)d_out;

  int n = in_sizes[0] / 128;  // N items
  // ws layout: y0 (bf16 copy of x0, 25.6MB) | x1 (bf16 layer-1 out, 25.6MB)
  u16x8* y0 = (u16x8*)d_ws;
  u16x8* x1 = (u16x8*)((char*)d_ws + (size_t)n * 128 * 2);

  float r = powf(5.0f + 1e-7f, -0.5f);
  float w = r * r;

  int n8 = n * 16;  // n*16 threads for cvt; also n*16 threads for layers
  int blocks = (n8 + 255) / 256;
  cvt_bf16<<<blocks, 256, 0, stream>>>((const f32x4*)x0, y0, n8);
  gcn_layer1<<<blocks, 256, 0, stream>>>(y0, knn, x1, w, n);
  gcn_layer2<<<blocks, 256, 0, stream>>>((const f32x4*)x0, x1, knn, out, w, n);
}

// Round 7
// 149.087 us; speedup vs baseline: 1.1937x; 1.0060x over previous
//
#include <hip/hip_runtime.h>
#include <math.h>

// Item_Graph: 2-layer fixed-degree GCN over KNN graph.
// N=100000, D=128, K=5. Edge weight is the CONSTANT w = 1/(5+1e-7).
//   x1 = w * gather-sum(x0);  out = x0 + x1 + w * gather-sum(x1)
// R6: (a) layer2 residual uses bf16 y0 (saves 25.6MB fp32 x0 stream;
//     err +<=0.04 vs 0.116 budget); (b) nontemporal LOADS on single-use
//     streams so the gather targets (y0, x1: 25.6MB each) keep cache
//     capacity. Gathers stay cached-path. Model: kernels run at the
//     memory system's effective rate on logical bytes (R4/R5 nulls ruled
//     out issue- and ILP-bound); only bytes + residency remain.

#define GCN_K 5

typedef float f32x4 __attribute__((ext_vector_type(4)));
typedef ushort u16x8 __attribute__((ext_vector_type(8)));  // 16B = 8 bf16

static __device__ __forceinline__ ushort f2bf(float f) {
  unsigned u = __float_as_uint(f);
  u = (u + 0x7fffu + ((u >> 16) & 1u)) >> 16;  // RTNE (no NaN inputs here)
  return (ushort)u;
}
static __device__ __forceinline__ float bf2f(ushort u) {
  return __uint_as_float(((unsigned)u) << 16);
}

// Streaming convert: y0 = bf16(x0). 8 floats per thread. NT loads (x0 is
// never read again), regular stores (y0 feeds layer1's gathers -> cache it).
__global__ __launch_bounds__(256) void cvt_bf16(
    const f32x4* __restrict__ x0, u16x8* __restrict__ y0, int n8) {
  int t = blockIdx.x * 256 + threadIdx.x;
  if (t >= n8) return;
  f32x4 a = __builtin_nontemporal_load(&x0[2 * t]);
  f32x4 b = __builtin_nontemporal_load(&x0[2 * t + 1]);
  u16x8 p;
  p[0] = f2bf(a.x); p[1] = f2bf(a.y); p[2] = f2bf(a.z); p[3] = f2bf(a.w);
  p[4] = f2bf(b.x); p[5] = f2bf(b.y); p[6] = f2bf(b.z); p[7] = f2bf(b.w);
  y0[t] = p;
}

// x1 = bf16(w * gather-sum(y0)). 16 lanes/row, 16B/lane.
__global__ __launch_bounds__(256) void gcn_layer1(
    const u16x8* __restrict__ y0, const int* __restrict__ knn,
    u16x8* __restrict__ x1, float w, int n) {
  int t = blockIdx.x * 256 + threadIdx.x;
  int row = t >> 4;
  if (row >= n) return;  // whole 16-lane group exits together (same row)
  int c = t & 15;
  int jv = 0;
  if (c < GCN_K) jv = knn[row * GCN_K + c];  // 5 loads per 16 lanes
  int j0 = __shfl(jv, 0, 16);
  int j1 = __shfl(jv, 1, 16);
  int j2 = __shfl(jv, 2, 16);
  int j3 = __shfl(jv, 3, 16);
  int j4 = __shfl(jv, 4, 16);
  u16x8 v0 = y0[(size_t)j0 * 16 + c];
  u16x8 v1 = y0[(size_t)j1 * 16 + c];
  u16x8 v2 = y0[(size_t)j2 * 16 + c];
  u16x8 v3 = y0[(size_t)j3 * 16 + c];
  u16x8 v4 = y0[(size_t)j4 * 16 + c];
  u16x8 p;
#pragma unroll
  for (int e = 0; e < 8; ++e) {
    float s = bf2f(v0[e]) + bf2f(v1[e]) + bf2f(v2[e]) + bf2f(v3[e]) +
              bf2f(v4[e]);
    p[e] = f2bf(w * s);
  }
  x1[(size_t)row * 16 + c] = p;  // regular store: layer2 gathers x1
}

// out = y0 + x1 + w * gather-sum(x1). 16 lanes/row, 8 floats/lane.
__global__ __launch_bounds__(256) void gcn_layer2(
    const u16x8* __restrict__ y0, const u16x8* __restrict__ x1,
    const int* __restrict__ knn, float* __restrict__ out, float w, int n) {
  int t = blockIdx.x * 256 + threadIdx.x;
  int row = t >> 4;
  if (row >= n) return;
  int c = t & 15;
  int jv = 0;
  if (c < GCN_K) jv = knn[row * GCN_K + c];
  int j0 = __shfl(jv, 0, 16);
  int j1 = __shfl(jv, 1, 16);
  int j2 = __shfl(jv, 2, 16);
  int j3 = __shfl(jv, 3, 16);
  int j4 = __shfl(jv, 4, 16);
  u16x8 v0 = x1[(size_t)j0 * 16 + c];
  u16x8 v1 = x1[(size_t)j1 * 16 + c];
  u16x8 v2 = x1[(size_t)j2 * 16 + c];
  u16x8 v3 = x1[(size_t)j3 * 16 + c];
  u16x8 v4 = x1[(size_t)j4 * 16 + c];
  // Own-row residual reads are single-use streams -> NT loads.
  u16x8 a = __builtin_nontemporal_load(&y0[(size_t)row * 16 + c]);
  u16x8 b = __builtin_nontemporal_load(&x1[(size_t)row * 16 + c]);
  float o[8];
#pragma unroll
  for (int e = 0; e < 8; ++e) {
    float s = bf2f(v0[e]) + bf2f(v1[e]) + bf2f(v2[e]) + bf2f(v3[e]) +
              bf2f(v4[e]);
    o[e] = bf2f(a[e]) + bf2f(b[e]) + w * s;
  }
  f32x4 q0, q1;
  q0.x = o[0]; q0.y = o[1]; q0.z = o[2]; q0.w = o[3];
  q1.x = o[4]; q1.y = o[5]; q1.z = o[6]; q1.w = o[7];
  f32x4* op = (f32x4*)(out + (size_t)row * 128 + c * 8);
  __builtin_nontemporal_store(q0, op);      // out is write-once stream:
  __builtin_nontemporal_store(q1, op + 1);  // keep L2/L3 for the gathers
}

extern "C" void kernel_launch(void* const* d_in, const int* in_sizes, int n_in,
                              void* d_out, int out_size, void* d_ws, size_t ws_size,
                              hipStream_t stream) {
  const float* x0 = (const float*)d_in[0];
  const int* knn = (const int*)d_in[1];
  float* out = (float*)d_out;

  int n = in_sizes[0] / 128;  // N items
  // ws layout: y0 (bf16 copy of x0, 25.6MB) | x1 (bf16 layer-1 out, 25.6MB)
  u16x8* y0 = (u16x8*)d_ws;
  u16x8* x1 = (u16x8*)((char*)d_ws + (size_t)n * 128 * 2);

  float r = powf(5.0f + 1e-7f, -0.5f);
  float w = r * r;

  int n8 = n * 16;  // n*16 threads for each kernel
  int blocks = (n8 + 255) / 256;
  cvt_bf16<<<blocks, 256, 0, stream>>>((const f32x4*)x0, y0, n8);
  gcn_layer1<<<blocks, 256, 0, stream>>>(y0, knn, x1, w, n);
  gcn_layer2<<<blocks, 256, 0, stream>>>(y0, x1, knn, out, w, n);
}